// Round 4
// baseline (179.324 us; speedup 1.0000x reference)
//
#include <hip/hip_runtime.h>
#include <stdint.h>

#define N_Q   65536
#define N_S   65536
#define NB_H  26
#define PAD_H 28
#define KP    10
#define CIN   64
#define COUT  128
#define MT    16   // query points per block
#define BM    16   // output rows per block

typedef unsigned short u16x8  __attribute__((ext_vector_type(8)));
typedef float          f32x4  __attribute__((ext_vector_type(4)));
typedef _Float16       f16x8  __attribute__((ext_vector_type(8)));
typedef unsigned int   u32x4  __attribute__((ext_vector_type(4)));

#define CVT_BLOCKS 2049   // ceil((N_S+1)*CIN/8 / 256)
#define PACK_BLOCKS 40    // ceil(8*20*64 / 256)

static __device__ __forceinline__ unsigned short f2h(float f) {
  return __builtin_bit_cast(unsigned short, (_Float16)f);
}

// v_cvt_pkrtz_f16_f32 packed to raw u32
static __device__ __forceinline__ unsigned int pkrtz_u32(float a, float b) {
  return __builtin_bit_cast(unsigned int, __builtin_amdgcn_cvt_pkrtz(a, b));
}

// ---- prep: x fp32 -> fp16 (+ zero shadow row) AND weight pack (fp16) --------
// Bpack[((ct*20 + ks)*64 + lane)*8 + j] = B[ks*32 + (lane>>4)*8 + j][ct*16 + (lane&15)]
__global__ void prep_kernel(const float* __restrict__ x,
                            const float* __restrict__ w,
                            unsigned short* __restrict__ xh,
                            unsigned short* __restrict__ bp) {
  if (blockIdx.x < CVT_BLOCKS) {
    long t = (long)blockIdx.x * blockDim.x + threadIdx.x;
    long off = t * 8;
    if (off >= (long)(N_S + 1) * CIN) return;
    u16x8 o;
    if (off < (long)N_S * CIN) {
      f32x4 a = *(const f32x4*)(x + off);
      f32x4 b = *(const f32x4*)(x + off + 4);
      o[0] = f2h(a[0]); o[1] = f2h(a[1]); o[2] = f2h(a[2]); o[3] = f2h(a[3]);
      o[4] = f2h(b[0]); o[5] = f2h(b[1]); o[6] = f2h(b[2]); o[7] = f2h(b[3]);
    } else {
      o = (u16x8)0;                       // shadow feature row = zeros
    }
    *(u16x8*)(xh + off) = o;
  } else {
    int t = (blockIdx.x - CVT_BLOCKS) * blockDim.x + threadIdx.x;
    if (t >= 8 * 20 * 64) return;
    int lane = t & 63;
    int frag = t >> 6;            // ct*20 + ks
    int ks = frag % 20;
    int ct = frag / 20;
    int row0 = ks * 32 + (lane >> 4) * 8;
    int col  = ct * 16 + (lane & 15);
    u16x8 o;
    #pragma unroll
    for (int j = 0; j < 8; ++j) o[j] = f2h(w[(row0 + j) * COUT + col]);
    *(u16x8*)(bp + (long)t * 8) = o;
  }
}

// LDS map:
//   smem_raw[20480]  : phases A/A2/B -> {nbr[16][80] (5120) | kp[16][30] (1920)}
//                      phase C onward -> sA (20 frags x 512 halves, XOR-swizzled)
//   wfrag[16*512]    : stage-1 A-frags (16x32 fp16 per m; k>=10 and h>=26 zero)
//   sh_ind[16][26]
// Total 38,528 B -> 4 blocks/CU.
#define SH_NBR(m, c) (((float*)smem_raw)[(m) * 80 + (c)])
#define SH_KP(m, r)  (((float*)(smem_raw + 5120))[(m) * 30 + (r)])

__global__ void __launch_bounds__(256, 4)
kpconv_fused(const float* __restrict__ q_pts, const float* __restrict__ s_pts,
             const float* __restrict__ gen_W, const float* __restrict__ gen_b,
             const int* __restrict__ inds, const unsigned short* __restrict__ xh,
             const unsigned short* __restrict__ bp, float* __restrict__ out) {

  __shared__ char           smem_raw[20480] __attribute__((aligned(16)));
  __shared__ unsigned short wfrag[16 * 512] __attribute__((aligned(16)));
  __shared__ int            sh_ind[MT][NB_H];

  unsigned short* sA = (unsigned short*)smem_raw;

  const int  tid  = threadIdx.x;
  const long row0 = (long)blockIdx.x * BM;

  // ---- memset wfrag (zero pad rows k>=10, h>=26) ----
  {
    unsigned int* wz = (unsigned int*)wfrag;
    #pragma unroll
    for (int i = 0; i < 16; ++i) wz[tid + 256 * i] = 0u;
  }

  // ---- Phase A: neighbors = s_pad[ind] - q; pad channels 78,79 = -1 ----
  for (int it = tid; it < MT * NB_H; it += 256) {
    int m = it / NB_H, h = it % NB_H;
    int n = (int)row0 + m;
    int ind = inds[n * NB_H + h];
    sh_ind[m][h] = ind;
    float sx, sy, sz;
    if ((unsigned)ind < (unsigned)N_S) {
      sx = s_pts[ind * 3 + 0]; sy = s_pts[ind * 3 + 1]; sz = s_pts[ind * 3 + 2];
    } else {
      sx = 1e6f; sy = 1e6f; sz = 1e6f;   // shadow support point
    }
    SH_NBR(m, h * 3 + 0) = sx - q_pts[n * 3 + 0];
    SH_NBR(m, h * 3 + 1) = sy - q_pts[n * 3 + 1];
    SH_NBR(m, h * 3 + 2) = sz - q_pts[n * 3 + 2];
  }
  if (tid < MT * 2) SH_NBR(tid >> 1, 78 + (tid & 1)) = -1.0f;
  __syncthreads();

  // ---- Phase A2: kp = padded @ gen_W^T + gen_b ----
  for (int it = tid; it < MT * KP * 3; it += 256) {
    int m = it / 30, r = it % 30;
    const float* Wr = gen_W + r * (PAD_H * 3);
    const f32x4* W4 = (const f32x4*)Wr;
    const f32x4* N4 = (const f32x4*)((float*)smem_raw + m * 80);
    f32x4 accv = {0.f, 0.f, 0.f, 0.f};
    #pragma unroll
    for (int j = 0; j < 20; ++j) accv += W4[j] * N4[j];
    SH_KP(m, r) = gen_b[r] - (Wr[80] + Wr[81] + Wr[82] + Wr[83])
                + accv[0] + accv[1] + accv[2] + accv[3];
  }
  __syncthreads();

  // ---- Phase B: w-pairs (h0,h1) -> wfrag A-frag layout ----
  // A-frag: lane l holds A[k = l&15][h = (l>>4)*8 + j]; halves addr
  //   m*512 + (h>>3)*128 + k*8 + (h&7).  half2 (h0,h0+1) -> one u32 write.
  for (int p = tid; p < MT * 13 * KP; p += 256) {
    int k = p % KP;
    int t = p / KP;            // 0..207
    int m = t & (MT - 1);
    int hp = t >> 4;           // 0..12
    float kx = SH_KP(m, k * 3 + 0), ky = SH_KP(m, k * 3 + 1), kz = SH_KP(m, k * 3 + 2);
    int h0 = hp * 2;
    float dx0 = SH_NBR(m, h0 * 3 + 0) - kx;
    float dy0 = SH_NBR(m, h0 * 3 + 1) - ky;
    float dz0 = SH_NBR(m, h0 * 3 + 2) - kz;
    float w0 = fmaxf(1.0f - sqrtf(dx0 * dx0 + dy0 * dy0 + dz0 * dz0) * (1.0f / 1.2f), 0.0f);
    float dx1 = SH_NBR(m, h0 * 3 + 3) - kx;
    float dy1 = SH_NBR(m, h0 * 3 + 4) - ky;
    float dz1 = SH_NBR(m, h0 * 3 + 5) - kz;
    float w1 = fmaxf(1.0f - sqrtf(dx1 * dx1 + dy1 * dy1 + dz1 * dz1) * (1.0f / 1.2f), 0.0f);
    *(unsigned int*)(wfrag + m * 512 + (h0 >> 3) * 128 + k * 8 + (h0 & 7)) =
        pkrtz_u32(w0, w1);
  }
  __syncthreads();   // nbr/kp dead from here; smem_raw becomes sA

  // ---- Phase C (stage-1 MFMA): weighted[m] = Wm(16x32) @ Xm(32x64) ----
  // Wave wv owns m = wv*4 .. wv*4+3.  B-frag gathered by u16 loads:
  //   lane l: col c = ct*16 + (l&15), rows h = (l>>4)*8 + j (h>=26 -> w=0).
  // D (f32, row k = (l>>4)*4+r, col c) -> sA halves
  //   ks*512 + ((kq*128 + m*8 + (e&7)) ^ ((ks>>3)&3)<<4),  ks=k*2+(c>>5),
  //   e=c&31, kq=e>>3.  Swizzle makes the 4 k-groups hit disjoint bank windows.
  {
    const int lane = tid & 63;
    const int wv   = tid >> 6;
    const int g    = lane >> 4;
    const int cl   = lane & 15;
    const unsigned short* xbase = xh + cl;

#define LOADM(MM, V)                                                          \
    {                                                                         \
      _Pragma("unroll")                                                       \
      for (int j = 0; j < 8; ++j) {                                           \
        int h = g * 8 + j;                                                    \
        int ind = sh_ind[MM][h < NB_H ? h : 0];                               \
        const unsigned short* pj = xbase + (long)ind * CIN;                   \
        _Pragma("unroll")                                                     \
        for (int ct = 0; ct < 4; ++ct) V[ct][j] = pj[ct * 16];                \
      }                                                                       \
    }

#define CONSUME(MM, V)                                                        \
    {                                                                         \
      u16x8 afr = *(const u16x8*)&wfrag[(MM) * 512 + (g * 16 + cl) * 8];      \
      f16x8 a = __builtin_bit_cast(f16x8, afr);                               \
      _Pragma("unroll")                                                       \
      for (int ct = 0; ct < 4; ++ct) {                                        \
        u32x4 bu;                                                             \
        bu[0] = V[ct][0] | (V[ct][1] << 16);                                  \
        bu[1] = V[ct][2] | (V[ct][3] << 16);                                  \
        bu[2] = V[ct][4] | (V[ct][5] << 16);                                  \
        bu[3] = V[ct][6] | (V[ct][7] << 16);                                  \
        f16x8 b = __builtin_bit_cast(f16x8, bu);                              \
        f32x4 d = __builtin_amdgcn_mfma_f32_16x16x32_f16(                     \
            a, b, (f32x4){0.f, 0.f, 0.f, 0.f}, 0, 0, 0);                      \
        const int e   = ((ct & 1) << 4) | cl;                                 \
        const int sj  = ((e >> 3) * 128) + (MM) * 8 + (e & 7);                \
        const int ct2 = ct >> 1;                                              \
        _Pragma("unroll")                                                     \
        for (int r = 0; r < 4; ++r) {                                         \
          int k = g * 4 + r;                                                  \
          if (k < KP) {                                                       \
            int ks = k * 2 + ct2;                                             \
            sA[ks * 512 + (sj ^ (((ks >> 3) & 3) << 4))] = f2h(d[r]);         \
          }                                                                   \
        }                                                                     \
      }                                                                       \
    }

    unsigned int v0[4][8], v1[4][8];
    const int m0 = wv * 4;
    LOADM(m0, v0)
    LOADM(m0 + 1, v1)
    CONSUME(m0, v0)
    LOADM(m0 + 2, v0)
    CONSUME(m0 + 1, v1)
    LOADM(m0 + 3, v1)
    CONSUME(m0 + 2, v0)
    CONSUME(m0 + 3, v1)
#undef LOADM
#undef CONSUME
  }
  __syncthreads();

  // ---- Stage-2 GEMM: out[16][128] = A[16][640] @ B[640][128] (fp16 MFMA) ----
  // 4 waves x 2 col-tiles; bp fragments prefetched depth-4 from L2;
  // A b128 reads at (lane*8) ^ swz(ks): conflict-free comb (uniform XOR/ks).
  {
    const int wave = tid >> 6;
    const int lane = tid & 63;
    const int ct0  = wave * 2, ct1 = ct0 + 1;

    f32x4 acc[2];
    acc[0] = (f32x4){0.f, 0.f, 0.f, 0.f};
    acc[1] = (f32x4){0.f, 0.f, 0.f, 0.f};

    u16x8 pb0[4], pb1[4];
    #pragma unroll
    for (int d = 0; d < 4; ++d) {
      pb0[d] = *(const u16x8*)(bp + (long)((ct0 * 20 + d) * 64 + lane) * 8);
      pb1[d] = *(const u16x8*)(bp + (long)((ct1 * 20 + d) * 64 + lane) * 8);
    }

    #pragma unroll
    for (int ks = 0; ks < 20; ++ks) {
      f16x8 b0 = __builtin_bit_cast(f16x8, pb0[ks & 3]);
      f16x8 b1 = __builtin_bit_cast(f16x8, pb1[ks & 3]);
      if (ks + 4 < 20) {
        pb0[ks & 3] = *(const u16x8*)(bp + (long)((ct0 * 20 + ks + 4) * 64 + lane) * 8);
        pb1[ks & 3] = *(const u16x8*)(bp + (long)((ct1 * 20 + ks + 4) * 64 + lane) * 8);
      }
      const int swzk = ((ks >> 3) & 3) << 4;
      u16x8 au = *(const u16x8*)&sA[ks * 512 + ((lane * 8) ^ swzk)];
      f16x8 a = __builtin_bit_cast(f16x8, au);
      acc[0] = __builtin_amdgcn_mfma_f32_16x16x32_f16(a, b0, acc[0], 0, 0, 0);
      acc[1] = __builtin_amdgcn_mfma_f32_16x16x32_f16(a, b1, acc[1], 0, 0, 0);
    }

    // C/D layout: col = lane&15, row = (lane>>4)*4 + reg  [measured m89/m91]
    const int col   = lane & 15;
    const int rbase = (lane >> 4) * 4;
    #pragma unroll
    for (int r = 0; r < 4; ++r) {
      long row = row0 + rbase + r;
      __builtin_nontemporal_store(acc[0][r], &out[row * COUT + ct0 * 16 + col]);
      __builtin_nontemporal_store(acc[1][r], &out[row * COUT + ct1 * 16 + col]);
    }
  }
}

extern "C" void kernel_launch(void* const* d_in, const int* in_sizes, int n_in,
                              void* d_out, int out_size, void* d_ws, size_t ws_size,
                              hipStream_t stream) {
  const float* q_pts = (const float*)d_in[0];
  const float* s_pts = (const float*)d_in[1];
  const float* x     = (const float*)d_in[2];
  const float* gen_W = (const float*)d_in[3];
  const float* gen_b = (const float*)d_in[4];
  const float* wts   = (const float*)d_in[5];
  const int*   inds  = (const int*)d_in[6];
  float* out = (float*)d_out;

  unsigned short* xh = (unsigned short*)d_ws;            // (N_S+1)*CIN fp16 = 8.39 MB
  unsigned short* bp = xh + (size_t)(N_S + 1) * CIN;     // 81920 fp16 = 160 KB

  prep_kernel<<<CVT_BLOCKS + PACK_BLOCKS, 256, 0, stream>>>(x, wts, xh, bp);
  kpconv_fused<<<N_Q / BM, 256, 0, stream>>>(q_pts, s_pts, gen_W, gen_b,
                                             inds, xh, bp, out);
}

// Round 5
// 169.852 us; speedup vs baseline: 1.0558x; 1.0558x over previous
//
#include <hip/hip_runtime.h>
#include <stdint.h>

#define N_Q   65536
#define N_S   65536
#define NB_H  26
#define PAD_H 28
#define KP    10
#define CIN   64
#define COUT  128
#define MT    16   // query points per block
#define BM    16   // output rows per block

typedef unsigned short u16x8  __attribute__((ext_vector_type(8)));
typedef float          f32x4  __attribute__((ext_vector_type(4)));
typedef _Float16       f16x8  __attribute__((ext_vector_type(8)));
typedef _Float16       f16x2  __attribute__((ext_vector_type(2)));
typedef unsigned int   u32x4  __attribute__((ext_vector_type(4)));
typedef unsigned int   u32x2  __attribute__((ext_vector_type(2)));

#define CVT_BLOCKS 2049   // ceil((N_S+1)*CIN/8 / 256)
#define PACK_BLOCKS 40    // ceil(8*20*64 / 256)

static __device__ __forceinline__ unsigned short f2h(float f) {
  return __builtin_bit_cast(unsigned short, (_Float16)f);
}

// v_cvt_pkrtz_f16_f32 packed to raw u32
static __device__ __forceinline__ unsigned int pkrtz_u32(float a, float b) {
  return __builtin_bit_cast(unsigned int, __builtin_amdgcn_cvt_pkrtz(a, b));
}

// half2-dot with fp32 accumulate: v_dot2_f32_f16
static __device__ __forceinline__ float fdot2u(unsigned int a, unsigned int b, float c) {
#if __has_builtin(__builtin_amdgcn_fdot2)
  return __builtin_amdgcn_fdot2(__builtin_bit_cast(f16x2, a),
                                __builtin_bit_cast(f16x2, b), c, false);
#else
  f16x2 ha = __builtin_bit_cast(f16x2, a), hb = __builtin_bit_cast(f16x2, b);
  return c + (float)ha[0] * (float)hb[0] + (float)ha[1] * (float)hb[1];
#endif
}

// ---- prep: x fp32 -> fp16 (+ zero shadow row) AND weight pack (fp16) --------
// Bpack[((ct*20 + ks)*64 + lane)*8 + j] = B[ks*32 + (lane>>4)*8 + j][ct*16 + (lane&15)]
__global__ void prep_kernel(const float* __restrict__ x,
                            const float* __restrict__ w,
                            unsigned short* __restrict__ xh,
                            unsigned short* __restrict__ bp) {
  if (blockIdx.x < CVT_BLOCKS) {
    long t = (long)blockIdx.x * blockDim.x + threadIdx.x;
    long off = t * 8;
    if (off >= (long)(N_S + 1) * CIN) return;
    u16x8 o;
    if (off < (long)N_S * CIN) {
      f32x4 a = *(const f32x4*)(x + off);
      f32x4 b = *(const f32x4*)(x + off + 4);
      o[0] = f2h(a[0]); o[1] = f2h(a[1]); o[2] = f2h(a[2]); o[3] = f2h(a[3]);
      o[4] = f2h(b[0]); o[5] = f2h(b[1]); o[6] = f2h(b[2]); o[7] = f2h(b[3]);
    } else {
      o = (u16x8)0;                       // shadow feature row = zeros
    }
    *(u16x8*)(xh + off) = o;
  } else {
    int t = (blockIdx.x - CVT_BLOCKS) * blockDim.x + threadIdx.x;
    if (t >= 8 * 20 * 64) return;
    int lane = t & 63;
    int frag = t >> 6;            // ct*20 + ks
    int ks = frag % 20;
    int ct = frag / 20;
    int row0 = ks * 32 + (lane >> 4) * 8;
    int col  = ct * 16 + (lane & 15);
    u16x8 o;
    #pragma unroll
    for (int j = 0; j < 8; ++j) o[j] = f2h(w[(row0 + j) * COUT + col]);
    *(u16x8*)(bp + (long)t * 8) = o;
  }
}

// ---- fused kernel: PER-WAVE pipeline (no block barriers until GEMM) ---------
// Round-4 lesson: shifting work between pipes inside the barrier-convoy
// structure doesn't help (dur pinned ~100us, VALU 35-49%). This round each
// wave owns rows m0..m0+3 end-to-end; block barriers -> intra-wave
// s_waitcnt lgkmcnt(0) fences; ONE __syncthreads before the GEMM.
// Phase-C gather prefetch issues BEFORE A2/B (hides L2 latency under compute).
// LDS: 1664 + 5120 + 1920 + 9984 + 20480 = 39,168 B -> 4 blocks/CU.
__global__ void __launch_bounds__(256, 4)
kpconv_fused(const float* __restrict__ q_pts, const float* __restrict__ s_pts,
             const float* __restrict__ gen_W, const float* __restrict__ gen_b,
             const int* __restrict__ inds, const unsigned short* __restrict__ xh,
             const unsigned short* __restrict__ bp, float* __restrict__ out) {

  __shared__ int            sh_ind[MT][NB_H];        // 1664 B
  __shared__ float          sh_nbr[MT][80];          // 5120 B (78 used + 2 pad=-1)
  __shared__ float          sh_kp[MT][KP * 3];       // 1920 B
  __shared__ unsigned int   sh_aw[MT][13][12];       // 9984 B (pad 10->12: 16B rows)
  __shared__ unsigned short sA[20 * 512];            // 20480 B (frag-major, XOR swz)

  const int  tid  = threadIdx.x;
  const int  lane = tid & 63;
  const int  wv   = tid >> 6;
  const int  m0   = wv * 4;                          // wave-owned rows m0..m0+3
  const long row0 = (long)blockIdx.x * BM;

  // ---- Phase A (per-wave): neighbors = s_pad[ind] - q; chans 78,79 = -1 ----
  #pragma unroll
  for (int it = 0; it < 2; ++it) {
    int idx = it * 64 + lane;
    if (idx < 4 * NB_H) {
      int m = m0 + idx / NB_H;
      int h = idx % NB_H;
      int n = (int)row0 + m;
      int ind = inds[n * NB_H + h];
      sh_ind[m][h] = ind;
      float sx, sy, sz;
      if ((unsigned)ind < (unsigned)N_S) {
        sx = s_pts[ind * 3 + 0]; sy = s_pts[ind * 3 + 1]; sz = s_pts[ind * 3 + 2];
      } else {
        sx = 1e6f; sy = 1e6f; sz = 1e6f;   // shadow support point
      }
      sh_nbr[m][h * 3 + 0] = sx - q_pts[n * 3 + 0];
      sh_nbr[m][h * 3 + 1] = sy - q_pts[n * 3 + 1];
      sh_nbr[m][h * 3 + 2] = sz - q_pts[n * 3 + 2];
    }
  }
  if (lane < 8) sh_nbr[m0 + (lane >> 1)][78 + (lane & 1)] = -1.0f;
  asm volatile("s_waitcnt lgkmcnt(0)" ::: "memory");   // wave-local fence

  // ---- Early phase-C gather prefetch (hides L2 latency under A2+B) ----
  const int il = lane & 31;
  const int g2 = lane >> 5;
  const int i0 = il * 2;
  const int rA = m0 + g2, rB = rA + 2;
  unsigned int xrA[8], xrB[8];
  #pragma unroll
  for (int h = 0; h < 8; ++h) {
    xrA[h] = *(const unsigned int*)(xh + (long)sh_ind[rA][h] * CIN + i0);
    xrB[h] = *(const unsigned int*)(xh + (long)sh_ind[rB][h] * CIN + i0);
  }

  // ---- Phase A2 (per-wave): kp = padded @ gen_W^T + gen_b ----
  #pragma unroll
  for (int it = 0; it < 2; ++it) {
    int idx = it * 64 + lane;
    if (idx < 4 * 30) {
      int m = m0 + idx / 30;
      int r = idx % 30;
      const float* Wr = gen_W + r * (PAD_H * 3);
      const f32x4* W4 = (const f32x4*)Wr;
      const f32x4* N4 = (const f32x4*)&sh_nbr[m][0];
      f32x4 accv = {0.f, 0.f, 0.f, 0.f};
      #pragma unroll
      for (int j = 0; j < 20; ++j) accv += W4[j] * N4[j];
      sh_kp[m][r] = gen_b[r] - (Wr[80] + Wr[81] + Wr[82] + Wr[83])
                  + accv[0] + accv[1] + accv[2] + accv[3];
    }
  }
  asm volatile("s_waitcnt lgkmcnt(0)" ::: "memory");   // wave-local fence

  // ---- Phase B (per-wave): w-pairs (h0,h1) per (m,hp,k), packed half2 ----
  for (int it = 0; it < 9; ++it) {
    int idx = it * 64 + lane;
    if (idx < 4 * 13 * KP) {
      int k  = idx % KP;
      int t  = idx / KP;         // 0..51
      int m  = m0 + (t & 3);
      int hp = t >> 2;           // 0..12
      float kx = sh_kp[m][k * 3 + 0], ky = sh_kp[m][k * 3 + 1], kz = sh_kp[m][k * 3 + 2];
      int h0 = hp * 2;
      float dx0 = sh_nbr[m][h0 * 3 + 0] - kx;
      float dy0 = sh_nbr[m][h0 * 3 + 1] - ky;
      float dz0 = sh_nbr[m][h0 * 3 + 2] - kz;
      float w0 = fmaxf(1.0f - sqrtf(dx0 * dx0 + dy0 * dy0 + dz0 * dz0) * (1.0f / 1.2f), 0.0f);
      float dx1 = sh_nbr[m][h0 * 3 + 3] - kx;
      float dy1 = sh_nbr[m][h0 * 3 + 4] - ky;
      float dz1 = sh_nbr[m][h0 * 3 + 5] - kz;
      float w1 = fmaxf(1.0f - sqrtf(dx1 * dx1 + dy1 * dy1 + dz1 * dz1) * (1.0f / 1.2f), 0.0f);
      sh_aw[m][hp][k] = pkrtz_u32(w0, w1);
    }
  }
  asm volatile("s_waitcnt lgkmcnt(0)" ::: "memory");   // wave-local fence

  // ---- Phase C (per-wave): rows rA,rB; depth-8 rotating prefetch; fdot2 ----
  {
    float a0A[KP], a1A[KP], a0B[KP], a1B[KP];
    #pragma unroll
    for (int k = 0; k < KP; ++k) { a0A[k] = 0.f; a1A[k] = 0.f; a0B[k] = 0.f; a1B[k] = 0.f; }

    #pragma unroll
    for (int p = 0; p < 13; ++p) {
      unsigned int r0A = xrA[(2 * p) & 7], r1A = xrA[(2 * p + 1) & 7];
      unsigned int r0B = xrB[(2 * p) & 7], r1B = xrB[(2 * p + 1) & 7];
      if (2 * p + 8 < NB_H) {
        xrA[(2 * p) & 7] = *(const unsigned int*)(xh + (long)sh_ind[rA][2 * p + 8] * CIN + i0);
        xrB[(2 * p) & 7] = *(const unsigned int*)(xh + (long)sh_ind[rB][2 * p + 8] * CIN + i0);
      }
      if (2 * p + 9 < NB_H) {
        xrA[(2 * p + 1) & 7] = *(const unsigned int*)(xh + (long)sh_ind[rA][2 * p + 9] * CIN + i0);
        xrB[(2 * p + 1) & 7] = *(const unsigned int*)(xh + (long)sh_ind[rB][2 * p + 9] * CIN + i0);
      }
      unsigned int p0A = __builtin_amdgcn_perm(r1A, r0A, 0x05040100u);
      unsigned int p1A = __builtin_amdgcn_perm(r1A, r0A, 0x07060302u);
      unsigned int p0B = __builtin_amdgcn_perm(r1B, r0B, 0x05040100u);
      unsigned int p1B = __builtin_amdgcn_perm(r1B, r0B, 0x07060302u);

      unsigned int wA[KP], wB[KP];
      *(u32x4*)&wA[0] = *(const u32x4*)&sh_aw[rA][p][0];
      *(u32x4*)&wA[4] = *(const u32x4*)&sh_aw[rA][p][4];
      *(u32x2*)&wA[8] = *(const u32x2*)&sh_aw[rA][p][8];
      *(u32x4*)&wB[0] = *(const u32x4*)&sh_aw[rB][p][0];
      *(u32x4*)&wB[4] = *(const u32x4*)&sh_aw[rB][p][4];
      *(u32x2*)&wB[8] = *(const u32x2*)&sh_aw[rB][p][8];

      #pragma unroll
      for (int k = 0; k < KP; ++k) {
        a0A[k] = fdot2u(wA[k], p0A, a0A[k]);
        a1A[k] = fdot2u(wA[k], p1A, a1A[k]);
        a0B[k] = fdot2u(wB[k], p0B, a0B[k]);
        a1B[k] = fdot2u(wB[k], p1B, a1B[k]);
      }
    }

    // swizzled frag store (verified R3): slot = kq*16+row;
    // half = slot*8 + j, XOR (kq<<3)^(qhi<<5); +qhi*512 frag parity
    const int kq  = (il & 15) >> 2;
    const int qhi = il >> 4;
    const int j2  = (2 * il) & 7;
    const int swz = (kq << 3) ^ (qhi << 5);
    const int hbA = (((kq * 16 + rA) * 8 + j2) ^ swz) + qhi * 512;
    const int hbB = (((kq * 16 + rB) * 8 + j2) ^ swz) + qhi * 512;
    #pragma unroll
    for (int k = 0; k < KP; ++k) {
      *(unsigned int*)(sA + k * 1024 + hbA) = pkrtz_u32(a0A[k], a1A[k]);
      *(unsigned int*)(sA + k * 1024 + hbB) = pkrtz_u32(a0B[k], a1B[k]);
    }
  }

  // ---- bp depth-4 prefetch BEFORE the barrier (hides under barrier wait) ----
  const int ct0 = wv * 2, ct1 = ct0 + 1;
  u16x8 pb0[4], pb1[4];
  #pragma unroll
  for (int d = 0; d < 4; ++d) {
    pb0[d] = *(const u16x8*)(bp + (long)((ct0 * 20 + d) * 64 + lane) * 8);
    pb1[d] = *(const u16x8*)(bp + (long)((ct1 * 20 + d) * 64 + lane) * 8);
  }

  __syncthreads();   // the ONLY block barrier: sA complete before GEMM

  // ---- GEMM: out[16][128] = A[16][640] @ B[640][128] (fp16 MFMA) ----
  {
    const int a0 = (lane * 8) ^ ((lane >> 4) << 3);   // halves within frag

    f32x4 acc[2];
    acc[0] = (f32x4){0.f, 0.f, 0.f, 0.f};
    acc[1] = (f32x4){0.f, 0.f, 0.f, 0.f};

    #pragma unroll
    for (int ks = 0; ks < 20; ++ks) {
      f16x8 b0 = __builtin_bit_cast(f16x8, pb0[ks & 3]);
      f16x8 b1 = __builtin_bit_cast(f16x8, pb1[ks & 3]);
      if (ks + 4 < 20) {
        pb0[ks & 3] = *(const u16x8*)(bp + (long)((ct0 * 20 + ks + 4) * 64 + lane) * 8);
        pb1[ks & 3] = *(const u16x8*)(bp + (long)((ct1 * 20 + ks + 4) * 64 + lane) * 8);
      }
      u16x8 au = *(const u16x8*)&sA[ks * 512 + (a0 ^ ((ks & 1) << 5))];
      f16x8 a = __builtin_bit_cast(f16x8, au);
      acc[0] = __builtin_amdgcn_mfma_f32_16x16x32_f16(a, b0, acc[0], 0, 0, 0);
      acc[1] = __builtin_amdgcn_mfma_f32_16x16x32_f16(a, b1, acc[1], 0, 0, 0);
    }

    // C/D layout: col = lane&15, row = (lane>>4)*4 + reg  [measured m89/m91]
    const int col   = lane & 15;
    const int rbase = (lane >> 4) * 4;
    #pragma unroll
    for (int r = 0; r < 4; ++r) {
      long row = row0 + rbase + r;
      __builtin_nontemporal_store(acc[0][r], &out[row * COUT + ct0 * 16 + col]);
      __builtin_nontemporal_store(acc[1][r], &out[row * COUT + ct1 * 16 + col]);
    }
  }
}

extern "C" void kernel_launch(void* const* d_in, const int* in_sizes, int n_in,
                              void* d_out, int out_size, void* d_ws, size_t ws_size,
                              hipStream_t stream) {
  const float* q_pts = (const float*)d_in[0];
  const float* s_pts = (const float*)d_in[1];
  const float* x     = (const float*)d_in[2];
  const float* gen_W = (const float*)d_in[3];
  const float* gen_b = (const float*)d_in[4];
  const float* wts   = (const float*)d_in[5];
  const int*   inds  = (const int*)d_in[6];
  float* out = (float*)d_out;

  unsigned short* xh = (unsigned short*)d_ws;            // (N_S+1)*CIN fp16 = 8.39 MB
  unsigned short* bp = xh + (size_t)(N_S + 1) * CIN;     // 81920 fp16 = 160 KB

  prep_kernel<<<CVT_BLOCKS + PACK_BLOCKS, 256, 0, stream>>>(x, wts, xh, bp);
  kpconv_fused<<<N_Q / BM, 256, 0, stream>>>(q_pts, s_pts, gen_W, gen_b,
                                             inds, xh, bp, out);
}